// Round 3
// baseline (177.649 us; speedup 1.0000x reference)
//
#include <hip/hip_runtime.h>
#include <hip/hip_bf16.h>
#include <math.h>

// Problem constants
#define BATCH   2048
#define TWO_B   4096
#define DIM     1024
#define NB      32            // 4096 / 128 tiles per side
#define NTILE   528           // NB*(NB+1)/2 triangle tiles (incl diagonal)
#define NBLK    1056          // 2 half-blocks (128x64) per tile
// 1 / (0.07 * ln(2)) : exp(s/T) = exp2(s * INV_T_LOG2E)
#define INV_T_LOG2E 20.60991907f
#define INV_T       14.285714285714286f

typedef __bf16  bf16x8 __attribute__((ext_vector_type(8)));
typedef float   f32x4  __attribute__((ext_vector_type(4)));

__device__ __forceinline__ unsigned short f2bf(float f) {
    union { float f; unsigned int u; } x; x.f = f;
    unsigned int u = x.u;
    return (unsigned short)((u + 0x7fffu + ((u >> 16) & 1u)) >> 16); // RNE
}

__device__ __forceinline__ void load_lds16(const void* g, void* l) {
    __builtin_amdgcn_global_load_lds(
        (const __attribute__((address_space(1))) void*)g,
        (__attribute__((address_space(3))) void*)l,
        16, 0, 0);
}

// ---------------------------------------------------------------------------
// Kernel 1: L2-normalize 4096 rows -> bf16 z[4096][1024]. Wave-per-row (no
// block barrier). Also zero-inits rowsum and the completion counter.
// ---------------------------------------------------------------------------
__global__ __launch_bounds__(256) void normalize_kernel(
        const float* __restrict__ feat, unsigned short* __restrict__ z,
        float* __restrict__ rowsum, unsigned int* __restrict__ counter) {
    const int lane = threadIdx.x & 63;
    const int row  = blockIdx.x * 4 + (threadIdx.x >> 6);
    if (lane == 0) rowsum[row] = 0.0f;
    if (blockIdx.x == 0 && threadIdx.x == 0) *counter = 0u;

    const float* src = feat + (row < BATCH ? (size_t)row * (2 * DIM)
                                           : (size_t)(row - BATCH) * (2 * DIM) + DIM);
    float4 v[4];
    float ss = 0.0f;
    #pragma unroll
    for (int t = 0; t < 4; ++t) {
        v[t] = ((const float4*)src)[t * 64 + lane];
        ss += v[t].x * v[t].x + v[t].y * v[t].y + v[t].z * v[t].z + v[t].w * v[t].w;
    }
    #pragma unroll
    for (int off = 32; off; off >>= 1) ss += __shfl_xor(ss, off, 64);
    const float scale = 1.0f / fmaxf(sqrtf(ss), 1e-12f);
    unsigned short* zrow = z + (size_t)row * DIM;
    #pragma unroll
    for (int t = 0; t < 4; ++t) {
        ushort4 o;
        o.x = f2bf(v[t].x * scale);
        o.y = f2bf(v[t].y * scale);
        o.z = f2bf(v[t].z * scale);
        o.w = f2bf(v[t].w * scale);
        ((ushort4*)zrow)[t * 64 + lane] = o;
    }
}

// ---------------------------------------------------------------------------
// Kernel 2: 1056 uniform 128x64 half-tile blocks covering the upper triangle
// of sim = z z^T (bf16 MFMA, BK=32, XOR-swizzled LDS -> 0 bank conflicts).
// Epilogue: rowsum[r] += sum exp(sim/T) (mask c==r); off-diag tiles also
// mirror into rowsum[c]; positives captured at c == r+2048. Last block
// (agent-scope counter) computes the final scalar loss.
// ---------------------------------------------------------------------------
__global__ __launch_bounds__(256, 5) void gemm_fused(
        const unsigned short* __restrict__ z,
        float* __restrict__ rowsum,
        float* __restrict__ positives,
        unsigned int* __restrict__ counter,
        float* __restrict__ out) {
    __shared__ __bf16 sA[128 * 32];   // 8 KB
    __shared__ __bf16 sB[64 * 32];    // 4 KB

    // block -> (tile, half); adjacent blocks share a tile (A-tile L2 reuse)
    const int half = blockIdx.x & 1;
    int rem = blockIdx.x >> 1, by = 0;
    while (rem >= NB - by) { rem -= NB - by; ++by; }
    const int bx = by + rem;
    const int rb = by * 128;
    const int cb = bx * 128 + half * 64;
    const bool mirror = (bx > by);

    const int tid  = threadIdx.x;
    const int lane = tid & 63;
    const int wv   = tid >> 6;       // wave 0..3
    const int wr   = wv >> 1;        // wave row (0..1) -> 64-row strip
    const int wc   = wv & 1;         // wave col (0..1) -> 32-col strip
    const int q    = lane >> 4;      // quad 0..3
    const int mn   = lane & 15;

    f32x4 acc[4][2] = {};

    const char* zb  = (const char*)z;                  // row stride = 2048 B
    const int lrow  = lane >> 2;                       // row within 16-row chunk
    // source-side XOR swizzle: LDS slot (l&3) of row (l>>2) holds K-segment
    // (l&3)^((l>>3)&3); read slot q^((row>>1)&3) is then 2-way (free)
    const int lsegb = (((lane & 3) ^ ((lane >> 3) & 3)) * 16);
    const int rslot = (q ^ ((mn >> 1) & 3)) * 8;       // element offset in row

    for (int k0 = 0; k0 < DIM; k0 += 32) {
        // A: 8 chunks of 16 rows, wave stages chunks 2wv, 2wv+1; B: chunk wv
        #pragma unroll
        for (int t = 0; t < 2; ++t) {
            const int ci = wv * 2 + t;
            const char* gA = zb + (size_t)(rb + ci * 16 + lrow) * 2048 + k0 * 2 + lsegb;
            load_lds16(gA, (char*)sA + ci * 1024);
        }
        const char* gB = zb + (size_t)(cb + wv * 16 + lrow) * 2048 + k0 * 2 + lsegb;
        load_lds16(gB, (char*)sB + wv * 1024);
        __syncthreads();

        bf16x8 af[4], bfv[2];
        #pragma unroll
        for (int i = 0; i < 4; ++i)
            af[i] = *(const bf16x8*)&sA[(wr * 64 + i * 16 + mn) * 32 + rslot];
        #pragma unroll
        for (int j = 0; j < 2; ++j)
            bfv[j] = *(const bf16x8*)&sB[(wc * 32 + j * 16 + mn) * 32 + rslot];
        #pragma unroll
        for (int i = 0; i < 4; ++i)
            #pragma unroll
            for (int j = 0; j < 2; ++j)
                acc[i][j] = __builtin_amdgcn_mfma_f32_16x16x32_bf16(
                                af[i], bfv[j], acc[i][j], 0, 0, 0);
        __syncthreads();
    }

    // Epilogue: C/D layout col = lane&15, row = (lane>>4)*4 + reg
    float colAcc[2] = {0.f, 0.f};
    #pragma unroll
    for (int i = 0; i < 4; ++i) {
        #pragma unroll
        for (int reg = 0; reg < 4; ++reg) {
            const int r = rb + wr * 64 + i * 16 + q * 4 + reg;
            float local = 0.0f;
            #pragma unroll
            for (int j = 0; j < 2; ++j) {
                const int c = cb + wc * 32 + j * 16 + mn;
                const float s = acc[i][j][reg];
                if (r < BATCH && c == r + BATCH) {   // positive pair + mirror
                    __hip_atomic_store(&positives[r], s, __ATOMIC_RELAXED,
                                       __HIP_MEMORY_SCOPE_AGENT);
                    __hip_atomic_store(&positives[c], s, __ATOMIC_RELAXED,
                                       __HIP_MEMORY_SCOPE_AGENT);
                }
                const float e = (c == r) ? 0.0f : exp2f(s * INV_T_LOG2E);
                local += e;
                colAcc[j] += e;
            }
            local += __shfl_xor(local, 1, 64);
            local += __shfl_xor(local, 2, 64);
            local += __shfl_xor(local, 4, 64);
            local += __shfl_xor(local, 8, 64);
            if (mn == 0) atomicAdd(&rowsum[r], local);
        }
    }
    if (mirror) {   // rowsum[c] += same exp values (symmetry)
        #pragma unroll
        for (int j = 0; j < 2; ++j) {
            float v = colAcc[j];
            v += __shfl_xor(v, 16, 64);
            v += __shfl_xor(v, 32, 64);
            if (q == 0) atomicAdd(&rowsum[cb + wc * 32 + j * 16 + mn], v);
        }
    }

    // ---- last-block finalize (threadfence-reduction, agent scope) ----
    __shared__ int amLast;
    __threadfence();
    __syncthreads();
    if (tid == 0) {
        unsigned int old = atomicAdd(counter, 1u);
        amLast = (old == NBLK - 1);
    }
    __syncthreads();
    if (amLast) {
        __threadfence();
        float acc2 = 0.0f;
        for (int r = tid; r < TWO_B; r += 256) {
            float rs = __hip_atomic_load(&rowsum[r], __ATOMIC_RELAXED,
                                         __HIP_MEMORY_SCOPE_AGENT);
            float p  = __hip_atomic_load(&positives[r], __ATOMIC_RELAXED,
                                         __HIP_MEMORY_SCOPE_AGENT);
            acc2 += logf(rs) - p * INV_T;
        }
        #pragma unroll
        for (int off = 32; off; off >>= 1) acc2 += __shfl_down(acc2, off, 64);
        __shared__ float s_part[4];
        if ((tid & 63) == 0) s_part[tid >> 6] = acc2;
        __syncthreads();
        if (tid == 0)
            out[0] = (s_part[0] + s_part[1] + s_part[2] + s_part[3]) * (1.0f / TWO_B);
    }
}

extern "C" void kernel_launch(void* const* d_in, const int* in_sizes, int n_in,
                              void* d_out, int out_size, void* d_ws, size_t ws_size,
                              hipStream_t stream) {
    const float* feat = (const float*)d_in[0];
    char* ws = (char*)d_ws;

    // workspace: z bf16[4096][1024] (8 MB) | rowsum f32[4096] | positives f32[4096] | counter
    unsigned short* z     = (unsigned short*)ws;
    float* rowsum         = (float*)(ws + (size_t)TWO_B * DIM * 2);
    float* positives      = rowsum + TWO_B;
    unsigned int* counter = (unsigned int*)(positives + TWO_B);
    float* out            = (float*)d_out;

    normalize_kernel<<<TWO_B / 4, 256, 0, stream>>>(feat, z, rowsum, counter);
    gemm_fused<<<NBLK, 256, 0, stream>>>(z, rowsum, positives, counter, out);
}

// Round 4
// 173.557 us; speedup vs baseline: 1.0236x; 1.0236x over previous
//
#include <hip/hip_runtime.h>
#include <hip/hip_bf16.h>
#include <math.h>

// Problem constants
#define BATCH   2048
#define TWO_B   4096
#define DIM     1024
#define NBLK2   1024          // 32x32 full tile grid
// 1 / (0.07 * ln(2)) : exp(s/T) = exp2(s * INV_T_LOG2E)
#define INV_T_LOG2E 20.60991907f
#define INV_T       14.285714285714286f

typedef __bf16  bf16x8 __attribute__((ext_vector_type(8)));
typedef float   f32x4  __attribute__((ext_vector_type(4)));

__device__ __forceinline__ unsigned short f2bf(float f) {
    union { float f; unsigned int u; } x; x.f = f;
    unsigned int u = x.u;
    return (unsigned short)((u + 0x7fffu + ((u >> 16) & 1u)) >> 16); // RNE
}

__device__ __forceinline__ void load_lds16(const void* g, void* l) {
    __builtin_amdgcn_global_load_lds(
        (const __attribute__((address_space(1))) void*)g,
        (__attribute__((address_space(3))) void*)l,
        16, 0, 0);
}

// ---------------------------------------------------------------------------
// Kernel 1: L2-normalize 4096 rows -> bf16 z[4096][1024]. Wave-per-row.
// Also zero-inits rowsum and the completion counter.
// ---------------------------------------------------------------------------
__global__ __launch_bounds__(256) void normalize_kernel(
        const float* __restrict__ feat, unsigned short* __restrict__ z,
        float* __restrict__ rowsum, unsigned int* __restrict__ counter) {
    const int lane = threadIdx.x & 63;
    const int row  = blockIdx.x * 4 + (threadIdx.x >> 6);
    if (lane == 0) rowsum[row] = 0.0f;
    if (blockIdx.x == 0 && threadIdx.x == 0) *counter = 0u;

    const float* src = feat + (row < BATCH ? (size_t)row * (2 * DIM)
                                           : (size_t)(row - BATCH) * (2 * DIM) + DIM);
    float4 v[4];
    float ss = 0.0f;
    #pragma unroll
    for (int t = 0; t < 4; ++t) {
        v[t] = ((const float4*)src)[t * 64 + lane];
        ss += v[t].x * v[t].x + v[t].y * v[t].y + v[t].z * v[t].z + v[t].w * v[t].w;
    }
    #pragma unroll
    for (int off = 32; off; off >>= 1) ss += __shfl_xor(ss, off, 64);
    const float scale = 1.0f / fmaxf(sqrtf(ss), 1e-12f);
    unsigned short* zrow = z + (size_t)row * DIM;
    #pragma unroll
    for (int t = 0; t < 4; ++t) {
        ushort4 o;
        o.x = f2bf(v[t].x * scale);
        o.y = f2bf(v[t].y * scale);
        o.z = f2bf(v[t].z * scale);
        o.w = f2bf(v[t].w * scale);
        ((ushort4*)zrow)[t * 64 + lane] = o;
    }
}

// ---------------------------------------------------------------------------
// Kernel 2: full sim = z z^T, 1024 blocks of 128x128, BK=64 (16 K-iters,
// 32 MFMA/wave/iter — halves barrier-drain count vs BK=32).
// XOR-swizzled LDS: row stride 128 B = 8 16B-slots; LDS slot s of row r
// holds K-segment s ^ (r&7), so fragment reads (fixed q,kk over mn=0..15)
// touch every bank group exactly twice -> conflict-free (validated R2/R3).
// Epilogue: rowsum[r] += sum_{c!=r} exp(sim/T); positives[r] at c=(r+B)&4095.
// Last block (agent-scope counter) computes the final scalar loss.
// ---------------------------------------------------------------------------
__global__ __launch_bounds__(256) void gemm_fused(
        const unsigned short* __restrict__ z,
        float* __restrict__ rowsum,
        float* __restrict__ positives,
        unsigned int* __restrict__ counter,
        float* __restrict__ out) {
    __shared__ __bf16 sA[128 * 64];   // 16 KB
    __shared__ __bf16 sB[128 * 64];   // 16 KB

    const int tid  = threadIdx.x;
    const int lane = tid & 63;
    const int wv   = tid >> 6;       // wave 0..3
    const int wr   = wv >> 1;        // wave row (0..1) -> 64-row subtile
    const int wc   = wv & 1;         // wave col (0..1) -> 64-col subtile
    const int q    = lane >> 4;      // quad 0..3
    const int mn   = lane & 15;
    const int rb   = blockIdx.y * 128;
    const int cb   = blockIdx.x * 128;

    f32x4 acc[4][4] = {};

    const char* zb  = (const char*)z;              // row stride = 2048 B
    const int srow  = lane >> 3;                   // row within 8-row chunk
    const int sseg  = (lane & 7) ^ (lane >> 3);    // swizzled K-seg to fetch

    for (int k0 = 0; k0 < DIM; k0 += 64) {
        // stage A,B tiles: 16 chunks of 8 rows x 128 B each; wave wv does 4
        #pragma unroll
        for (int t = 0; t < 4; ++t) {
            const int c = wv * 4 + t;
            const char* gA = zb + (size_t)(rb + c * 8 + srow) * 2048 + k0 * 2 + sseg * 16;
            const char* gB = zb + (size_t)(cb + c * 8 + srow) * 2048 + k0 * 2 + sseg * 16;
            load_lds16(gA, (char*)sA + c * 1024);  // dest = base + lane*16
            load_lds16(gB, (char*)sB + c * 1024);
        }
        __syncthreads();

        #pragma unroll
        for (int kk = 0; kk < 2; ++kk) {
            const int slot = ((q + 4 * kk) ^ (mn & 7)) * 16;  // byte offset
            bf16x8 af[4], bfv[4];
            #pragma unroll
            for (int i = 0; i < 4; ++i)
                af[i] = *(const bf16x8*)((const char*)sA +
                            (wr * 64 + i * 16 + mn) * 128 + slot);
            #pragma unroll
            for (int j = 0; j < 4; ++j)
                bfv[j] = *(const bf16x8*)((const char*)sB +
                            (wc * 64 + j * 16 + mn) * 128 + slot);
            #pragma unroll
            for (int i = 0; i < 4; ++i)
                #pragma unroll
                for (int j = 0; j < 4; ++j)
                    acc[i][j] = __builtin_amdgcn_mfma_f32_16x16x32_bf16(
                                    af[i], bfv[j], acc[i][j], 0, 0, 0);
        }
        __syncthreads();
    }

    // Epilogue: C/D layout col = lane&15, row = (lane>>4)*4 + reg
    #pragma unroll
    for (int i = 0; i < 4; ++i) {
        #pragma unroll
        for (int reg = 0; reg < 4; ++reg) {
            const int r  = rb + wr * 64 + i * 16 + q * 4 + reg;
            const int pc = (r + BATCH) & (TWO_B - 1);
            float local = 0.0f;
            #pragma unroll
            for (int j = 0; j < 4; ++j) {
                const int c = cb + wc * 64 + j * 16 + mn;
                const float s = acc[i][j][reg];
                if (c == pc)
                    __hip_atomic_store(&positives[r], s, __ATOMIC_RELAXED,
                                       __HIP_MEMORY_SCOPE_AGENT);
                local += (c == r) ? 0.0f : exp2f(s * INV_T_LOG2E);
            }
            local += __shfl_xor(local, 1, 64);
            local += __shfl_xor(local, 2, 64);
            local += __shfl_xor(local, 4, 64);
            local += __shfl_xor(local, 8, 64);
            if (mn == 0) atomicAdd(&rowsum[r], local);
        }
    }

    // ---- last-block finalize (threadfence-reduction, agent scope) ----
    __shared__ int amLast;
    __threadfence();
    __syncthreads();
    if (tid == 0) {
        unsigned int old = atomicAdd(counter, 1u);
        amLast = (old == NBLK2 - 1);
    }
    __syncthreads();
    if (amLast) {
        __threadfence();
        float acc2 = 0.0f;
        for (int r = tid; r < TWO_B; r += 256) {
            float rs = __hip_atomic_load(&rowsum[r], __ATOMIC_RELAXED,
                                         __HIP_MEMORY_SCOPE_AGENT);
            float p  = __hip_atomic_load(&positives[r], __ATOMIC_RELAXED,
                                         __HIP_MEMORY_SCOPE_AGENT);
            acc2 += logf(rs) - p * INV_T;
        }
        #pragma unroll
        for (int off = 32; off; off >>= 1) acc2 += __shfl_down(acc2, off, 64);
        __shared__ float s_part[4];
        if ((tid & 63) == 0) s_part[tid >> 6] = acc2;
        __syncthreads();
        if (tid == 0)
            out[0] = (s_part[0] + s_part[1] + s_part[2] + s_part[3]) * (1.0f / TWO_B);
    }
}

extern "C" void kernel_launch(void* const* d_in, const int* in_sizes, int n_in,
                              void* d_out, int out_size, void* d_ws, size_t ws_size,
                              hipStream_t stream) {
    const float* feat = (const float*)d_in[0];
    char* ws = (char*)d_ws;

    // workspace: z bf16[4096][1024] (8 MB) | rowsum f32[4096] | positives f32[4096] | counter
    unsigned short* z     = (unsigned short*)ws;
    float* rowsum         = (float*)(ws + (size_t)TWO_B * DIM * 2);
    float* positives      = rowsum + TWO_B;
    unsigned int* counter = (unsigned int*)(positives + TWO_B);
    float* out            = (float*)d_out;

    normalize_kernel<<<TWO_B / 4, 256, 0, stream>>>(feat, z, rowsum, counter);
    gemm_fused<<<dim3(32, 32), 256, 0, stream>>>(z, rowsum, positives, counter, out);
}

// Round 5
// 134.030 us; speedup vs baseline: 1.3254x; 1.2949x over previous
//
#include <hip/hip_runtime.h>
#include <hip/hip_bf16.h>
#include <math.h>

// Problem constants
#define BATCH   2048
#define TWO_B   4096
#define DIM     1024
// 1 / (0.07 * ln(2)) : exp(s/T) = exp2(s * INV_T_LOG2E)
#define INV_T_LOG2E 20.60991907f
#define INV_T       14.285714285714286f

typedef __bf16  bf16x8 __attribute__((ext_vector_type(8)));
typedef float   f32x4  __attribute__((ext_vector_type(4)));

__device__ __forceinline__ unsigned short f2bf(float f) {
    union { float f; unsigned int u; } x; x.f = f;
    unsigned int u = x.u;
    return (unsigned short)((u + 0x7fffu + ((u >> 16) & 1u)) >> 16); // RNE
}

__device__ __forceinline__ void load_lds16(const void* g, void* l) {
    __builtin_amdgcn_global_load_lds(
        (const __attribute__((address_space(1))) void*)g,
        (__attribute__((address_space(3))) void*)l,
        16, 0, 0);
}

// ---------------------------------------------------------------------------
// Kernel 1: L2-normalize 4096 rows -> bf16 z[4096][1024]. Wave-per-row.
// Zero-inits rowsum (re-poisoned to 0xAA by the harness each call).
// NO device-scope fences anywhere in the hot kernels (R2-R4 lesson: the
// per-block agent fence forces XCD L2 writebacks and halves GEMM throughput).
// ---------------------------------------------------------------------------
__global__ __launch_bounds__(256) void normalize_kernel(
        const float* __restrict__ feat, unsigned short* __restrict__ z,
        float* __restrict__ rowsum) {
    const int lane = threadIdx.x & 63;
    const int row  = blockIdx.x * 4 + (threadIdx.x >> 6);
    if (lane == 0) rowsum[row] = 0.0f;

    const float* src = feat + (row < BATCH ? (size_t)row * (2 * DIM)
                                           : (size_t)(row - BATCH) * (2 * DIM) + DIM);
    float4 v[4];
    float ss = 0.0f;
    #pragma unroll
    for (int t = 0; t < 4; ++t) {
        v[t] = ((const float4*)src)[t * 64 + lane];
        ss += v[t].x * v[t].x + v[t].y * v[t].y + v[t].z * v[t].z + v[t].w * v[t].w;
    }
    #pragma unroll
    for (int off = 32; off; off >>= 1) ss += __shfl_xor(ss, off, 64);
    const float scale = 1.0f / fmaxf(sqrtf(ss), 1e-12f);
    unsigned short* zrow = z + (size_t)row * DIM;
    #pragma unroll
    for (int t = 0; t < 4; ++t) {
        ushort4 o;
        o.x = f2bf(v[t].x * scale);
        o.y = f2bf(v[t].y * scale);
        o.z = f2bf(v[t].z * scale);
        o.w = f2bf(v[t].w * scale);
        ((ushort4*)zrow)[t * 64 + lane] = o;
    }
}

// ---------------------------------------------------------------------------
// Kernel 2: full sim = z z^T, 1024 blocks of 128x128, BK=32, double-buffered
// LDS with prefetch-first ordering (next tile's global_load_lds issued BEFORE
// computing on the current buffer, so the vmcnt(0) drain at the barrier is
// covered by ~300 cyc of ds_read+MFMA).
// XOR-swizzled LDS (validated 0-conflict in R2/R3): K-seg s of row r stored
// at slot s^((r>>1)&3); fragment read slot q^((mn>>1)&3).
// Epilogue: rowsum[r] += sum_{c!=r} exp(sim/T); positives[r] at c=(r+B)&4095.
// Plain stores/atomics only — no fences (R1 structure, proven fastest).
// ---------------------------------------------------------------------------
__global__ __launch_bounds__(256) void gemm_fused(
        const unsigned short* __restrict__ z,
        float* __restrict__ rowsum,
        float* __restrict__ positives) {
    __shared__ __bf16 sA[2][128 * 32];   // 2 x 8 KB
    __shared__ __bf16 sB[2][128 * 32];   // 2 x 8 KB

    const int tid  = threadIdx.x;
    const int lane = tid & 63;
    const int wv   = tid >> 6;       // wave 0..3
    const int wr   = wv >> 1;        // wave row (0..1) -> 64-row subtile
    const int wc   = wv & 1;         // wave col (0..1) -> 64-col subtile
    const int q    = lane >> 4;      // quad 0..3
    const int mn   = lane & 15;
    const int rb   = blockIdx.y * 128;
    const int cb   = blockIdx.x * 128;

    f32x4 acc[4][4] = {};

    const char* zb  = (const char*)z;                  // row stride = 2048 B
    const int lrow  = lane >> 2;                       // row within 16-row chunk
    // fetch-side swizzle: lane (row=l>>2, slot=l&3) fetches K-seg
    // (l&3)^((l>>3)&3) so LDS slot s of row r holds seg s^((r>>1)&3)
    const int lsegb = (((lane & 3) ^ ((lane >> 3) & 3)) * 16);
    const int rslot = (q ^ ((mn >> 1) & 3)) * 8;       // element offset in row

    // per-wave staging chunks: ci = 2*wv, 2*wv+1 (16 rows x 64 B each)
    const size_t aoff0 = (size_t)(rb + (wv * 2 + 0) * 16 + lrow) * 2048 + lsegb;
    const size_t aoff1 = (size_t)(rb + (wv * 2 + 1) * 16 + lrow) * 2048 + lsegb;
    const size_t boff0 = (size_t)(cb + (wv * 2 + 0) * 16 + lrow) * 2048 + lsegb;
    const size_t boff1 = (size_t)(cb + (wv * 2 + 1) * 16 + lrow) * 2048 + lsegb;

    // preload k0 = 0 into buffer 0
    load_lds16(zb + aoff0, (char*)sA[0] + (wv * 2 + 0) * 1024);
    load_lds16(zb + aoff1, (char*)sA[0] + (wv * 2 + 1) * 1024);
    load_lds16(zb + boff0, (char*)sB[0] + (wv * 2 + 0) * 1024);
    load_lds16(zb + boff1, (char*)sB[0] + (wv * 2 + 1) * 1024);
    __syncthreads();

    int cur = 0;
    for (int k0 = 32; k0 <= DIM; k0 += 32) {
        // prefetch next K-tile into the other buffer (before compute!)
        if (k0 < DIM) {
            const int nxt = cur ^ 1;
            load_lds16(zb + aoff0 + k0 * 2, (char*)sA[nxt] + (wv * 2 + 0) * 1024);
            load_lds16(zb + aoff1 + k0 * 2, (char*)sA[nxt] + (wv * 2 + 1) * 1024);
            load_lds16(zb + boff0 + k0 * 2, (char*)sB[nxt] + (wv * 2 + 0) * 1024);
            load_lds16(zb + boff1 + k0 * 2, (char*)sB[nxt] + (wv * 2 + 1) * 1024);
        }
        // compute on current buffer
        bf16x8 af[4], bfv[4];
        #pragma unroll
        for (int i = 0; i < 4; ++i) {
            af[i]  = *(const bf16x8*)&sA[cur][(wr * 64 + i * 16 + mn) * 32 + rslot];
            bfv[i] = *(const bf16x8*)&sB[cur][(wc * 64 + i * 16 + mn) * 32 + rslot];
        }
        #pragma unroll
        for (int i = 0; i < 4; ++i)
            #pragma unroll
            for (int j = 0; j < 4; ++j)
                acc[i][j] = __builtin_amdgcn_mfma_f32_16x16x32_bf16(
                                af[i], bfv[j], acc[i][j], 0, 0, 0);
        __syncthreads();   // drains prefetch (covered) + guards buffer swap
        cur ^= 1;
    }

    // Epilogue: C/D layout col = lane&15, row = (lane>>4)*4 + reg
    #pragma unroll
    for (int i = 0; i < 4; ++i) {
        #pragma unroll
        for (int reg = 0; reg < 4; ++reg) {
            const int r  = rb + wr * 64 + i * 16 + q * 4 + reg;
            const int pc = (r + BATCH) & (TWO_B - 1);
            float local = 0.0f;
            #pragma unroll
            for (int j = 0; j < 4; ++j) {
                const int c = cb + wc * 64 + j * 16 + mn;
                const float s = acc[i][j][reg];
                if (c == pc) positives[r] = s;   // exactly one writer per r
                local += (c == r) ? 0.0f : exp2f(s * INV_T_LOG2E);
            }
            local += __shfl_xor(local, 1, 64);
            local += __shfl_xor(local, 2, 64);
            local += __shfl_xor(local, 4, 64);
            local += __shfl_xor(local, 8, 64);
            if (mn == 0) atomicAdd(&rowsum[r], local);
        }
    }
}

// ---------------------------------------------------------------------------
// Kernel 3: loss = mean_r( log(rowsum[r]) - positives[r]/T )
// ---------------------------------------------------------------------------
__global__ __launch_bounds__(256) void finalize_kernel(
        const float* __restrict__ rowsum,
        const float* __restrict__ positives,
        float* __restrict__ out) {
    float acc = 0.0f;
    for (int r = threadIdx.x; r < TWO_B; r += 256)
        acc += logf(rowsum[r]) - positives[r] * INV_T;
    #pragma unroll
    for (int off = 32; off; off >>= 1) acc += __shfl_down(acc, off, 64);
    __shared__ float s_part[4];
    if ((threadIdx.x & 63) == 0) s_part[threadIdx.x >> 6] = acc;
    __syncthreads();
    if (threadIdx.x == 0)
        out[0] = (s_part[0] + s_part[1] + s_part[2] + s_part[3]) * (1.0f / TWO_B);
}

extern "C" void kernel_launch(void* const* d_in, const int* in_sizes, int n_in,
                              void* d_out, int out_size, void* d_ws, size_t ws_size,
                              hipStream_t stream) {
    const float* feat = (const float*)d_in[0];
    char* ws = (char*)d_ws;

    // workspace: z bf16[4096][1024] (8 MB) | rowsum f32[4096] | positives f32[4096]
    unsigned short* z  = (unsigned short*)ws;
    float* rowsum      = (float*)(ws + (size_t)TWO_B * DIM * 2);
    float* positives   = rowsum + TWO_B;
    float* out         = (float*)d_out;

    normalize_kernel<<<TWO_B / 4, 256, 0, stream>>>(feat, z, rowsum);
    gemm_fused<<<dim3(32, 32), 256, 0, stream>>>(z, rowsum, positives);
    finalize_kernel<<<1, 256, 0, stream>>>(rowsum, positives, out);
}

// Round 6
// 112.400 us; speedup vs baseline: 1.5805x; 1.1924x over previous
//
#include <hip/hip_runtime.h>
#include <hip/hip_bf16.h>
#include <math.h>

// Problem constants
#define BATCH   2048
#define TWO_B   4096
#define DIM     1024
// 1 / (0.07 * ln(2)) : exp(s/T) = exp2(s * INV_T_LOG2E)
#define INV_T_LOG2E 20.60991907f
#define INV_T       14.285714285714286f

typedef float f32x4 __attribute__((ext_vector_type(4)));
typedef long  i64x2 __attribute__((ext_vector_type(2)));

__device__ __forceinline__ void load_lds16(const void* g, void* l) {
    __builtin_amdgcn_global_load_lds(
        (const __attribute__((address_space(1))) void*)g,
        (__attribute__((address_space(3))) void*)l,
        16, 0, 0);
}

// ---------------------------------------------------------------------------
// Kernel 1: L2-normalize 4096 rows -> fp8 e4m3 z[4096][1024] (4 MB).
// Wave-per-row; zero-inits rowsum. No device-scope fences (R2-R4 lesson:
// per-block agent fences force XCD L2 writebacks and halve GEMM throughput).
// ---------------------------------------------------------------------------
__global__ __launch_bounds__(256) void normalize_kernel(
        const float* __restrict__ feat, char* __restrict__ z,
        float* __restrict__ rowsum) {
    const int lane = threadIdx.x & 63;
    const int row  = blockIdx.x * 4 + (threadIdx.x >> 6);
    if (lane == 0) rowsum[row] = 0.0f;

    const float* src = feat + (row < BATCH ? (size_t)row * (2 * DIM)
                                           : (size_t)(row - BATCH) * (2 * DIM) + DIM);
    float4 v[4];
    float ss = 0.0f;
    #pragma unroll
    for (int t = 0; t < 4; ++t) {
        v[t] = ((const float4*)src)[t * 64 + lane];
        ss += v[t].x * v[t].x + v[t].y * v[t].y + v[t].z * v[t].z + v[t].w * v[t].w;
    }
    #pragma unroll
    for (int off = 32; off; off >>= 1) ss += __shfl_xor(ss, off, 64);
    const float scale = 1.0f / fmaxf(sqrtf(ss), 1e-12f);
    int4 o;
    int* op = (int*)&o;
    #pragma unroll
    for (int t = 0; t < 4; ++t) {
        int lo = __builtin_amdgcn_cvt_pk_fp8_f32(v[t].x * scale, v[t].y * scale, 0, false);
        op[t]  = __builtin_amdgcn_cvt_pk_fp8_f32(v[t].z * scale, v[t].w * scale, lo, true);
    }
    // 64 lanes x 16 B = 1024 B = one row
    ((int4*)(z + (size_t)row * DIM))[lane] = o;
}

// ---------------------------------------------------------------------------
// Kernel 2: full sim = z z^T in fp8 e4m3. 1024 blocks of 128x128, BK=64
// bytes (16 K-iters — half of bf16), double-buffered LDS.
// Staging: contiguous 64-B K-rows; lane q's ds_read_b128 covers global
// k in [16q,16q+16): first 8 B feed MFMA kstep0, second 8 B kstep1. This
// permutes K identically for A and B -> dot product invariant.
// XOR swizzle identical to R5's validated-conflict-free one (row = 64 B).
// Per wave-iter: 8 ds_read_b128 -> 32 mfma_16x16x32_fp8 (2x FLOP/LDS-byte
// vs bf16). Epilogue: rowsum[r] += sum_{c!=r} exp(sim/T); positives at
// c=(r+B)&4095. Plain stores/atomics only — no fences.
// ---------------------------------------------------------------------------
__global__ __launch_bounds__(256) void gemm_fused(
        const char* __restrict__ z,
        float* __restrict__ rowsum,
        float* __restrict__ positives) {
    __shared__ char sA[2][128 * 64];   // 2 x 8 KB
    __shared__ char sB[2][128 * 64];   // 2 x 8 KB

    const int tid  = threadIdx.x;
    const int lane = tid & 63;
    const int wv   = tid >> 6;       // wave 0..3
    const int wr   = wv >> 1;        // wave row (0..1) -> 64-row subtile
    const int wc   = wv & 1;         // wave col (0..1) -> 64-col subtile
    const int q    = lane >> 4;      // quad 0..3
    const int mn   = lane & 15;
    const int rb   = blockIdx.y * 128;
    const int cb   = blockIdx.x * 128;

    f32x4 acc[4][4] = {};

    const int lrow  = lane >> 2;                       // row within 16-row chunk
    // fetch-side swizzle (validated R2/R3/R5): lane slot l&3 fetches K-seg
    // (l&3)^((l>>3)&3) so LDS slot s of row r holds seg s^((r>>1)&3)
    const int lsegb = ((lane & 3) ^ ((lane >> 3) & 3)) * 16;
    const int rslot = (q ^ ((mn >> 1) & 3)) * 16;      // byte offset in 64-B row

    // per-wave staging chunks: ci = 2*wv, 2*wv+1 (16 rows x 64 B = 1 KB each)
    const size_t aoff0 = (size_t)(rb + (wv * 2 + 0) * 16 + lrow) * DIM + lsegb;
    const size_t aoff1 = (size_t)(rb + (wv * 2 + 1) * 16 + lrow) * DIM + lsegb;
    const size_t boff0 = (size_t)(cb + (wv * 2 + 0) * 16 + lrow) * DIM + lsegb;
    const size_t boff1 = (size_t)(cb + (wv * 2 + 1) * 16 + lrow) * DIM + lsegb;

    // preload K-tile 0 into buffer 0
    load_lds16(z + aoff0, sA[0] + (wv * 2 + 0) * 1024);
    load_lds16(z + aoff1, sA[0] + (wv * 2 + 1) * 1024);
    load_lds16(z + boff0, sB[0] + (wv * 2 + 0) * 1024);
    load_lds16(z + boff1, sB[0] + (wv * 2 + 1) * 1024);
    __syncthreads();

    int cur = 0;
    for (int k0 = 64; k0 <= DIM; k0 += 64) {
        if (k0 < DIM) {   // prefetch next K-tile into the other buffer
            const int nxt = cur ^ 1;
            load_lds16(z + aoff0 + k0, sA[nxt] + (wv * 2 + 0) * 1024);
            load_lds16(z + aoff1 + k0, sA[nxt] + (wv * 2 + 1) * 1024);
            load_lds16(z + boff0 + k0, sB[nxt] + (wv * 2 + 0) * 1024);
            load_lds16(z + boff1 + k0, sB[nxt] + (wv * 2 + 1) * 1024);
        }
        long a0[4], a1[4], b0[4], b1[4];
        #pragma unroll
        for (int i = 0; i < 4; ++i) {
            i64x2 va = *(const i64x2*)&sA[cur][(wr * 64 + i * 16 + mn) * 64 + rslot];
            a0[i] = va.x; a1[i] = va.y;
            i64x2 vb = *(const i64x2*)&sB[cur][(wc * 64 + i * 16 + mn) * 64 + rslot];
            b0[i] = vb.x; b1[i] = vb.y;
        }
        #pragma unroll
        for (int i = 0; i < 4; ++i)
            #pragma unroll
            for (int j = 0; j < 4; ++j) {
                acc[i][j] = __builtin_amdgcn_mfma_f32_16x16x32_fp8_fp8(
                                a0[i], b0[j], acc[i][j], 0, 0, 0);
                acc[i][j] = __builtin_amdgcn_mfma_f32_16x16x32_fp8_fp8(
                                a1[i], b1[j], acc[i][j], 0, 0, 0);
            }
        __syncthreads();
        cur ^= 1;
    }

    // Epilogue: C/D layout col = lane&15, row = (lane>>4)*4 + reg
    #pragma unroll
    for (int i = 0; i < 4; ++i) {
        #pragma unroll
        for (int reg = 0; reg < 4; ++reg) {
            const int r  = rb + wr * 64 + i * 16 + q * 4 + reg;
            const int pc = (r + BATCH) & (TWO_B - 1);
            float local = 0.0f;
            #pragma unroll
            for (int j = 0; j < 4; ++j) {
                const int c = cb + wc * 64 + j * 16 + mn;
                const float s = acc[i][j][reg];
                if (c == pc) positives[r] = s;   // exactly one writer per r
                local += (c == r) ? 0.0f : exp2f(s * INV_T_LOG2E);
            }
            local += __shfl_xor(local, 1, 64);
            local += __shfl_xor(local, 2, 64);
            local += __shfl_xor(local, 4, 64);
            local += __shfl_xor(local, 8, 64);
            if (mn == 0) atomicAdd(&rowsum[r], local);
        }
    }
}

// ---------------------------------------------------------------------------
// Kernel 3: loss = mean_r( log(rowsum[r]) - positives[r]/T )
// ---------------------------------------------------------------------------
__global__ __launch_bounds__(256) void finalize_kernel(
        const float* __restrict__ rowsum,
        const float* __restrict__ positives,
        float* __restrict__ out) {
    float acc = 0.0f;
    for (int r = threadIdx.x; r < TWO_B; r += 256)
        acc += logf(rowsum[r]) - positives[r] * INV_T;
    #pragma unroll
    for (int off = 32; off; off >>= 1) acc += __shfl_down(acc, off, 64);
    __shared__ float s_part[4];
    if ((threadIdx.x & 63) == 0) s_part[threadIdx.x >> 6] = acc;
    __syncthreads();
    if (threadIdx.x == 0)
        out[0] = (s_part[0] + s_part[1] + s_part[2] + s_part[3]) * (1.0f / TWO_B);
}

extern "C" void kernel_launch(void* const* d_in, const int* in_sizes, int n_in,
                              void* d_out, int out_size, void* d_ws, size_t ws_size,
                              hipStream_t stream) {
    const float* feat = (const float*)d_in[0];
    char* ws = (char*)d_ws;

    // workspace: z fp8[4096][1024] (4 MB) | rowsum f32[4096] | positives f32[4096]
    char* zq         = ws;
    float* rowsum    = (float*)(ws + (size_t)TWO_B * DIM);
    float* positives = rowsum + TWO_B;
    float* out       = (float*)d_out;

    normalize_kernel<<<TWO_B / 4, 256, 0, stream>>>(feat, zq, rowsum);
    gemm_fused<<<dim3(32, 32), 256, 0, stream>>>(zq, rowsum, positives);
    finalize_kernel<<<1, 256, 0, stream>>>(rowsum, positives, out);
}

// Round 7
// 107.247 us; speedup vs baseline: 1.6564x; 1.0480x over previous
//
#include <hip/hip_runtime.h>
#include <hip/hip_bf16.h>
#include <math.h>

// Problem constants
#define BATCH   2048
#define TWO_B   4096
#define DIM     1024
#define NBLK2   1024          // 32x32 grid of 128x128 tiles
// 1 / (0.07 * ln(2)) : exp(s/T) = exp2(s * INV_T_LOG2E)
#define INV_T_LOG2E 20.60991907f
#define INV_T       14.285714285714286f

typedef float f32x4 __attribute__((ext_vector_type(4)));
typedef long  i64x2 __attribute__((ext_vector_type(2)));

__device__ __forceinline__ void load_lds16(const void* g, void* l) {
    __builtin_amdgcn_global_load_lds(
        (const __attribute__((address_space(1))) void*)g,
        (__attribute__((address_space(3))) void*)l,
        16, 0, 0);
}

// ---------------------------------------------------------------------------
// Kernel 1: L2-normalize 4096 rows -> fp8 e4m3 z[4096][1024] (4 MB).
// Wave-per-row; zero-inits rowsum + completion counter. No fences.
// ---------------------------------------------------------------------------
__global__ __launch_bounds__(256) void normalize_kernel(
        const float* __restrict__ feat, char* __restrict__ z,
        float* __restrict__ rowsum, unsigned int* __restrict__ counter) {
    const int lane = threadIdx.x & 63;
    const int row  = blockIdx.x * 4 + (threadIdx.x >> 6);
    if (lane == 0) rowsum[row] = 0.0f;
    if (blockIdx.x == 0 && threadIdx.x == 0) *counter = 0u;

    const float* src = feat + (row < BATCH ? (size_t)row * (2 * DIM)
                                           : (size_t)(row - BATCH) * (2 * DIM) + DIM);
    float4 v[4];
    float ss = 0.0f;
    #pragma unroll
    for (int t = 0; t < 4; ++t) {
        v[t] = ((const float4*)src)[t * 64 + lane];
        ss += v[t].x * v[t].x + v[t].y * v[t].y + v[t].z * v[t].z + v[t].w * v[t].w;
    }
    #pragma unroll
    for (int off = 32; off; off >>= 1) ss += __shfl_xor(ss, off, 64);
    const float scale = 1.0f / fmaxf(sqrtf(ss), 1e-12f);
    int4 o;
    int* op = (int*)&o;
    #pragma unroll
    for (int t = 0; t < 4; ++t) {
        int lo = __builtin_amdgcn_cvt_pk_fp8_f32(v[t].x * scale, v[t].y * scale, 0, false);
        op[t]  = __builtin_amdgcn_cvt_pk_fp8_f32(v[t].z * scale, v[t].w * scale, lo, true);
    }
    ((int4*)(z + (size_t)row * DIM))[lane] = o;   // 64 lanes x 16 B = one row
}

// ---------------------------------------------------------------------------
// Kernel 2: full sim = z z^T in fp8 e4m3. 1024 blocks of 128x128, BK=128
// (8 K-iters — half the staging-drain events of R6), single 32 KB LDS buffer
// (dbuf at BK=128 would be 64 KB -> occupancy cliff, m132).
// Swizzle: 128-B rows = 8 16B-slots; slot s of row r holds K-seg s^(r&7)
// (staged via source-permuted lane addresses); read slot q^(r&7) retrieves
// seg q -> row-dependence cancels, K-permutation identical for A and B,
// 2 lanes/bank-group = conflict-free.
// Epilogue: rowsum[r] += sum_{c!=r} exp(sim/T) (device-scope atomicAdd),
// positives at c=(r+B)&4095 (agent relaxed atomic store). Fence-FREE
// last-block finalize: __syncthreads' implicit vmcnt(0) drains each wave's
// atomic acks; relaxed agent counter RMW; no L2 writeback ops (R2-R4 lesson).
// ---------------------------------------------------------------------------
__global__ __launch_bounds__(256) void gemm_fused(
        const char* __restrict__ z,
        float* __restrict__ rowsum,
        float* __restrict__ positives,
        unsigned int* __restrict__ counter,
        float* __restrict__ out) {
    __shared__ char sA[128 * 128];   // 16 KB
    __shared__ char sB[128 * 128];   // 16 KB

    const int tid  = threadIdx.x;
    const int lane = tid & 63;
    const int wv   = tid >> 6;       // wave 0..3
    const int wr   = wv >> 1;        // wave row (0..1) -> 64-row subtile
    const int wc   = wv & 1;         // wave col (0..1) -> 64-col subtile
    const int q    = lane >> 4;      // quad 0..3
    const int mn   = lane & 15;
    const int rb   = blockIdx.y * 128;
    const int cb   = blockIdx.x * 128;

    f32x4 acc[4][4] = {};

    // staging: chunk = 8 rows x 128 B = 1 KB; 16 chunks per matrix; wave
    // stages chunks 4wv..4wv+3. lane l: row l>>3, slot l&7, fetches K-seg
    // (l&7)^((l>>3)&7) so LDS slot s of row r holds seg s^(r&7).
    const int lrow  = lane >> 3;
    const int lsegb = ((lane & 7) ^ (lrow & 7)) * 16;
    // fragment read slots (row&7 == mn&7 since tile row offsets are x16):
    const int s1 = ((q    ) ^ (mn & 7)) * 16;   // K-seg q      (k in [16q,16q+16))
    const int s2 = ((q + 4) ^ (mn & 7)) * 16;   // K-seg q+4

    for (int k0 = 0; k0 < DIM; k0 += 128) {
        #pragma unroll
        for (int t = 0; t < 4; ++t) {
            const int c = wv * 4 + t;
            load_lds16(z + (size_t)(rb + c * 8 + lrow) * DIM + k0 + lsegb, sA + c * 1024);
            load_lds16(z + (size_t)(cb + c * 8 + lrow) * DIM + k0 + lsegb, sB + c * 1024);
        }
        __syncthreads();   // staging complete (vmcnt drain — 8 total now)

        long a0[4], a1[4], b0[4], b1[4];
        // K-steps 0,1 (seg q: first/second 8 B)
        #pragma unroll
        for (int i = 0; i < 4; ++i) {
            i64x2 v = *(const i64x2*)&sA[(wr * 64 + i * 16 + mn) * 128 + s1];
            a0[i] = v.x; a1[i] = v.y;
        }
        #pragma unroll
        for (int j = 0; j < 4; ++j) {
            i64x2 v = *(const i64x2*)&sB[(wc * 64 + j * 16 + mn) * 128 + s1];
            b0[j] = v.x; b1[j] = v.y;
        }
        #pragma unroll
        for (int i = 0; i < 4; ++i)
            #pragma unroll
            for (int j = 0; j < 4; ++j) {
                acc[i][j] = __builtin_amdgcn_mfma_f32_16x16x32_fp8_fp8(
                                a0[i], b0[j], acc[i][j], 0, 0, 0);
                acc[i][j] = __builtin_amdgcn_mfma_f32_16x16x32_fp8_fp8(
                                a1[i], b1[j], acc[i][j], 0, 0, 0);
            }
        // K-steps 2,3 (seg q+4)
        #pragma unroll
        for (int i = 0; i < 4; ++i) {
            i64x2 v = *(const i64x2*)&sA[(wr * 64 + i * 16 + mn) * 128 + s2];
            a0[i] = v.x; a1[i] = v.y;
        }
        #pragma unroll
        for (int j = 0; j < 4; ++j) {
            i64x2 v = *(const i64x2*)&sB[(wc * 64 + j * 16 + mn) * 128 + s2];
            b0[j] = v.x; b1[j] = v.y;
        }
        #pragma unroll
        for (int i = 0; i < 4; ++i)
            #pragma unroll
            for (int j = 0; j < 4; ++j) {
                acc[i][j] = __builtin_amdgcn_mfma_f32_16x16x32_fp8_fp8(
                                a0[i], b0[j], acc[i][j], 0, 0, 0);
                acc[i][j] = __builtin_amdgcn_mfma_f32_16x16x32_fp8_fp8(
                                a1[i], b1[j], acc[i][j], 0, 0, 0);
            }
        __syncthreads();   // all waves done reading before next overwrite
    }

    // Epilogue: C/D layout col = lane&15, row = (lane>>4)*4 + reg
    #pragma unroll
    for (int i = 0; i < 4; ++i) {
        #pragma unroll
        for (int reg = 0; reg < 4; ++reg) {
            const int r  = rb + wr * 64 + i * 16 + q * 4 + reg;
            const int pc = (r + BATCH) & (TWO_B - 1);
            float local = 0.0f;
            #pragma unroll
            for (int j = 0; j < 4; ++j) {
                const int c = cb + wc * 64 + j * 16 + mn;
                const float s = acc[i][j][reg];
                if (c == pc)   // unique writer per r; coherent-point store
                    __hip_atomic_store(&positives[r], s, __ATOMIC_RELAXED,
                                       __HIP_MEMORY_SCOPE_AGENT);
                local += (c == r) ? 0.0f : exp2f(s * INV_T_LOG2E);
            }
            local += __shfl_xor(local, 1, 64);
            local += __shfl_xor(local, 2, 64);
            local += __shfl_xor(local, 4, 64);
            local += __shfl_xor(local, 8, 64);
            if (mn == 0) atomicAdd(&rowsum[r], local);
        }
    }

    // ---- fence-free last-block finalize ----
    // __syncthreads lowers with s_waitcnt vmcnt(0): every wave's atomics are
    // acked (= complete at the device-coherent point) before tid 0 bumps the
    // counter. No __threadfence -> no L2 writeback storm (R2-R4 regression).
    __shared__ int amLast;
    __syncthreads();
    if (tid == 0) {
        unsigned int old = __hip_atomic_fetch_add(counter, 1u, __ATOMIC_RELAXED,
                                                  __HIP_MEMORY_SCOPE_AGENT);
        amLast = (old == NBLK2 - 1);
    }
    __syncthreads();
    if (amLast) {
        float acc2 = 0.0f;
        for (int r = tid; r < TWO_B; r += 256) {
            float rs = __hip_atomic_load(&rowsum[r], __ATOMIC_RELAXED,
                                         __HIP_MEMORY_SCOPE_AGENT);
            float p  = __hip_atomic_load(&positives[r], __ATOMIC_RELAXED,
                                         __HIP_MEMORY_SCOPE_AGENT);
            acc2 += logf(rs) - p * INV_T;
        }
        #pragma unroll
        for (int off = 32; off; off >>= 1) acc2 += __shfl_down(acc2, off, 64);
        __shared__ float s_part[4];
        if ((tid & 63) == 0) s_part[tid >> 6] = acc2;
        __syncthreads();
        if (tid == 0)
            out[0] = (s_part[0] + s_part[1] + s_part[2] + s_part[3]) * (1.0f / TWO_B);
    }
}

extern "C" void kernel_launch(void* const* d_in, const int* in_sizes, int n_in,
                              void* d_out, int out_size, void* d_ws, size_t ws_size,
                              hipStream_t stream) {
    const float* feat = (const float*)d_in[0];
    char* ws = (char*)d_ws;

    // workspace: z fp8[4096][1024] (4 MB) | rowsum f32[4096] | positives f32[4096] | counter
    char* zq              = ws;
    float* rowsum         = (float*)(ws + (size_t)TWO_B * DIM);
    float* positives      = rowsum + TWO_B;
    unsigned int* counter = (unsigned int*)(positives + TWO_B);
    float* out            = (float*)d_out;

    normalize_kernel<<<TWO_B / 4, 256, 0, stream>>>(feat, zq, rowsum, counter);
    gemm_fused<<<dim3(32, 32), 256, 0, stream>>>(zq, rowsum, positives, counter, out);
}

// Round 8
// 101.918 us; speedup vs baseline: 1.7431x; 1.0523x over previous
//
#include <hip/hip_runtime.h>
#include <hip/hip_bf16.h>
#include <math.h>

// Problem constants
#define BATCH   2048
#define TWO_B   4096
#define DIM     1024
#define NBLK2   1024          // 32x32 grid of 128x128 tiles
// 1 / (0.07 * ln(2)) : exp(s/T) = exp2(s * INV_T_LOG2E)
#define INV_T_LOG2E 20.60991907f
#define INV_T       14.285714285714286f

typedef float f32x4 __attribute__((ext_vector_type(4)));
typedef long  i64x2 __attribute__((ext_vector_type(2)));

__device__ __forceinline__ void load_lds16(const void* g, void* l) {
    __builtin_amdgcn_global_load_lds(
        (const __attribute__((address_space(1))) void*)g,
        (__attribute__((address_space(3))) void*)l,
        16, 0, 0);
}

// ---------------------------------------------------------------------------
// Kernel 1: L2-normalize 4096 rows -> fp8 e4m3 z[4096][1024] (4 MB).
// Wave-per-row; zero-inits rowsum + completion counter. No fences.
// ---------------------------------------------------------------------------
__global__ __launch_bounds__(256) void normalize_kernel(
        const float* __restrict__ feat, char* __restrict__ z,
        float* __restrict__ rowsum, unsigned int* __restrict__ counter) {
    const int lane = threadIdx.x & 63;
    const int row  = blockIdx.x * 4 + (threadIdx.x >> 6);
    if (lane == 0) rowsum[row] = 0.0f;
    if (blockIdx.x == 0 && threadIdx.x == 0) *counter = 0u;

    const float* src = feat + (row < BATCH ? (size_t)row * (2 * DIM)
                                           : (size_t)(row - BATCH) * (2 * DIM) + DIM);
    float4 v[4];
    float ss = 0.0f;
    #pragma unroll
    for (int t = 0; t < 4; ++t) {
        v[t] = ((const float4*)src)[t * 64 + lane];
        ss += v[t].x * v[t].x + v[t].y * v[t].y + v[t].z * v[t].z + v[t].w * v[t].w;
    }
    #pragma unroll
    for (int off = 32; off; off >>= 1) ss += __shfl_xor(ss, off, 64);
    const float scale = 1.0f / fmaxf(sqrtf(ss), 1e-12f);
    int4 o;
    int* op = (int*)&o;
    #pragma unroll
    for (int t = 0; t < 4; ++t) {
        int lo = __builtin_amdgcn_cvt_pk_fp8_f32(v[t].x * scale, v[t].y * scale, 0, false);
        op[t]  = __builtin_amdgcn_cvt_pk_fp8_f32(v[t].z * scale, v[t].w * scale, lo, true);
    }
    ((int4*)(z + (size_t)row * DIM))[lane] = o;   // 64 lanes x 16 B = one row
}

// ---------------------------------------------------------------------------
// Kernel 2: full sim = z z^T in fp8 e4m3. R6's proven-best K-loop (BK=64,
// double-buffered, XOR swizzle -> 0 conflicts) with:
//  * XCD-aware block swizzle: region k (8x16 blocks) -> blocks with id&7==k,
//    so each XCD's L2 holds only 8 A-panels + 16 B-panels = 3 MB < 4 MB.
//  * LDS-transpose epilogue: wave-private scratch (reusing tile LDS), one
//    coalesced 64-lane atomicAdd per wave instead of 64 shfl + 16 atomics.
//  * Fence-free last-block finalize (R7, proven): no L2 writeback ops.
// ---------------------------------------------------------------------------
__global__ __launch_bounds__(256) void gemm_fused(
        const char* __restrict__ z,
        float* __restrict__ rowsum,
        float* __restrict__ positives,
        unsigned int* __restrict__ counter,
        float* __restrict__ out) {
    __shared__ char smem[32768];     // 2x8KB sA dbuf | 2x8KB sB dbuf

    // XCD-aware swizzle: id&7 tracks the round-robin XCD assignment; give
    // XCD k an 8x16 block region so its L2 working set is 3 MB (< 4 MB).
    const int bid = blockIdx.x;
    const int xcd = bid & 7;
    const int t8  = bid >> 3;                   // 0..127 within region
    const int by  = (xcd >> 1) * 8 + (t8 & 7);
    const int bx  = (xcd & 1) * 16 + (t8 >> 3);
    const int rb  = by * 128;
    const int cb  = bx * 128;

    const int tid  = threadIdx.x;
    const int lane = tid & 63;
    const int wv   = tid >> 6;       // wave 0..3
    const int wr   = wv >> 1;        // wave row (0..1) -> 64-row subtile
    const int wc   = wv & 1;         // wave col (0..1) -> 64-col subtile
    const int q    = lane >> 4;      // quad 0..3
    const int mn   = lane & 15;

    char* sA0 = smem;                // sA[buf] = smem + buf*8192
    char* sB0 = smem + 16384;        // sB[buf] = smem + 16384 + buf*8192

    f32x4 acc[4][4] = {};

    const int lrow  = lane >> 2;                       // row within 16-row chunk
    // fetch-side swizzle (validated R2/R3/R5/R6): lane slot l&3 fetches K-seg
    // (l&3)^((l>>3)&3) so LDS slot s of row r holds seg s^((r>>1)&3)
    const int lsegb = ((lane & 3) ^ ((lane >> 3) & 3)) * 16;
    const int rslot = (q ^ ((mn >> 1) & 3)) * 16;      // byte offset in 64-B row

    // per-wave staging chunks: ci = 2*wv, 2*wv+1 (16 rows x 64 B = 1 KB each)
    const size_t aoff0 = (size_t)(rb + (wv * 2 + 0) * 16 + lrow) * DIM + lsegb;
    const size_t aoff1 = (size_t)(rb + (wv * 2 + 1) * 16 + lrow) * DIM + lsegb;
    const size_t boff0 = (size_t)(cb + (wv * 2 + 0) * 16 + lrow) * DIM + lsegb;
    const size_t boff1 = (size_t)(cb + (wv * 2 + 1) * 16 + lrow) * DIM + lsegb;

    // preload K-tile 0 into buffer 0
    load_lds16(z + aoff0, sA0 + (wv * 2 + 0) * 1024);
    load_lds16(z + aoff1, sA0 + (wv * 2 + 1) * 1024);
    load_lds16(z + boff0, sB0 + (wv * 2 + 0) * 1024);
    load_lds16(z + boff1, sB0 + (wv * 2 + 1) * 1024);
    __syncthreads();

    int cur = 0;
    for (int k0 = 64; k0 <= DIM; k0 += 64) {
        if (k0 < DIM) {   // prefetch next K-tile into the other buffer
            const int nxt = cur ^ 1;
            load_lds16(z + aoff0 + k0, sA0 + nxt * 8192 + (wv * 2 + 0) * 1024);
            load_lds16(z + aoff1 + k0, sA0 + nxt * 8192 + (wv * 2 + 1) * 1024);
            load_lds16(z + boff0 + k0, sB0 + nxt * 8192 + (wv * 2 + 0) * 1024);
            load_lds16(z + boff1 + k0, sB0 + nxt * 8192 + (wv * 2 + 1) * 1024);
        }
        const char* cA = sA0 + cur * 8192;
        const char* cB = sB0 + cur * 8192;
        long a0[4], a1[4], b0[4], b1[4];
        #pragma unroll
        for (int i = 0; i < 4; ++i) {
            i64x2 va = *(const i64x2*)&cA[(wr * 64 + i * 16 + mn) * 64 + rslot];
            a0[i] = va.x; a1[i] = va.y;
            i64x2 vb = *(const i64x2*)&cB[(wc * 64 + i * 16 + mn) * 64 + rslot];
            b0[i] = vb.x; b1[i] = vb.y;
        }
        #pragma unroll
        for (int i = 0; i < 4; ++i)
            #pragma unroll
            for (int j = 0; j < 4; ++j) {
                acc[i][j] = __builtin_amdgcn_mfma_f32_16x16x32_fp8_fp8(
                                a0[i], b0[j], acc[i][j], 0, 0, 0);
                acc[i][j] = __builtin_amdgcn_mfma_f32_16x16x32_fp8_fp8(
                                a1[i], b1[j], acc[i][j], 0, 0, 0);
            }
        __syncthreads();
        cur ^= 1;
    }

    // ---- Epilogue (C/D layout col = lane&15, row = (lane>>4)*4 + reg) ----
    // Wave-private LDS transpose: partials[row 0..63][colgroup mn 0..15],
    // row stride 20 floats (80 B: 16B-aligned, 2-way banks on write).
    float* ep = (float*)smem + wv * (64 * 20);
    #pragma unroll
    for (int i = 0; i < 4; ++i) {
        #pragma unroll
        for (int reg = 0; reg < 4; ++reg) {
            const int r  = rb + wr * 64 + i * 16 + q * 4 + reg;
            const int pc = (r + BATCH) & (TWO_B - 1);
            float local = 0.0f;
            #pragma unroll
            for (int j = 0; j < 4; ++j) {
                const int c = cb + wc * 64 + j * 16 + mn;
                const float s = acc[i][j][reg];
                if (c == pc)   // unique writer per r
                    __hip_atomic_store(&positives[r], s, __ATOMIC_RELAXED,
                                       __HIP_MEMORY_SCOPE_AGENT);
                local += (c == r) ? 0.0f : exp2f(s * INV_T_LOG2E);
            }
            ep[(i * 16 + q * 4 + reg) * 20 + mn] = local;
        }
    }
    // wave-private read-back (compiler inserts lgkmcnt wait); no barrier needed
    {
        const float4 p0 = *(const float4*)&ep[lane * 20 + 0];
        const float4 p1 = *(const float4*)&ep[lane * 20 + 4];
        const float4 p2 = *(const float4*)&ep[lane * 20 + 8];
        const float4 p3 = *(const float4*)&ep[lane * 20 + 12];
        const float tot = (p0.x + p0.y + p0.z + p0.w) + (p1.x + p1.y + p1.z + p1.w)
                        + (p2.x + p2.y + p2.z + p2.w) + (p3.x + p3.y + p3.z + p3.w);
        atomicAdd(&rowsum[rb + wr * 64 + lane], tot);   // 64-lane coalesced atomic
    }

    // ---- fence-free last-block finalize (R7, proven) ----
    __shared__ int amLast;
    __syncthreads();
    if (tid == 0) {
        unsigned int old = __hip_atomic_fetch_add(counter, 1u, __ATOMIC_RELAXED,
                                                  __HIP_MEMORY_SCOPE_AGENT);
        amLast = (old == NBLK2 - 1);
    }
    __syncthreads();
    if (amLast) {
        float acc2 = 0.0f;
        for (int r = tid; r < TWO_B; r += 256) {
            float rs = __hip_atomic_load(&rowsum[r], __ATOMIC_RELAXED,
                                         __HIP_MEMORY_SCOPE_AGENT);
            float p  = __hip_atomic_load(&positives[r], __ATOMIC_RELAXED,
                                         __HIP_MEMORY_SCOPE_AGENT);
            acc2 += logf(rs) - p * INV_T;
        }
        #pragma unroll
        for (int off = 32; off; off >>= 1) acc2 += __shfl_down(acc2, off, 64);
        __shared__ float s_part[4];
        if ((tid & 63) == 0) s_part[tid >> 6] = acc2;
        __syncthreads();
        if (tid == 0)
            out[0] = (s_part[0] + s_part[1] + s_part[2] + s_part[3]) * (1.0f / TWO_B);
    }
}

extern "C" void kernel_launch(void* const* d_in, const int* in_sizes, int n_in,
                              void* d_out, int out_size, void* d_ws, size_t ws_size,
                              hipStream_t stream) {
    const float* feat = (const float*)d_in[0];
    char* ws = (char*)d_ws;

    // workspace: z fp8[4096][1024] (4 MB) | rowsum f32[4096] | positives f32[4096] | counter
    char* zq              = ws;
    float* rowsum         = (float*)(ws + (size_t)TWO_B * DIM);
    float* positives      = rowsum + TWO_B;
    unsigned int* counter = (unsigned int*)(positives + TWO_B);
    float* out            = (float*)d_out;

    normalize_kernel<<<TWO_B / 4, 256, 0, stream>>>(feat, zq, rowsum, counter);
    gemm_fused<<<NBLK2, 256, 0, stream>>>(zq, rowsum, positives, counter, out);
}